// Round 6
// baseline (443.997 us; speedup 1.0000x reference)
//
#include <hip/hip_runtime.h>
#include <hip/hip_bf16.h>

#define FD 128

typedef __attribute__((ext_vector_type(8))) short bf16x8;
typedef __attribute__((ext_vector_type(4))) float f32x4;

__device__ __forceinline__ float bfu2f(unsigned short u) {
  return __uint_as_float(((unsigned int)u) << 16);
}
__device__ __forceinline__ float b2f(__hip_bfloat16 v) { return __bfloat162float(v); }
__device__ __forceinline__ unsigned int pk2(float lo, float hi) {
  return (unsigned int)__bfloat16_as_ushort(__float2bfloat16(lo)) |
         ((unsigned int)__bfloat16_as_ushort(__float2bfloat16(hi)) << 16);
}

// flag-dispatched external loads: ff=1 -> fp32, ff=0 -> bf16 ; fi=1 -> int64
__device__ __forceinline__ float ldf(const void* p, int i, int ff) {
  return ff ? ((const float*)p)[i] : b2f(((const __hip_bfloat16*)p)[i]);
}
__device__ __forceinline__ int ldi(const void* p, int i, int fi) {
  return fi ? (int)((const long long*)p)[i] : ((const int*)p)[i];
}

// ---- convert edge arrays + inline dtype detection + column histogram ------
// Every block sniffs dtypes locally (cheap, L2-hot); block 0 publishes flags
// for downstream kernels. Removes the separate detect_k launch.
__global__ void cvtall_k(const void* __restrict__ rows, const void* __restrict__ cols,
                         const void* __restrict__ vals, int nnz, int n,
                         const void* __restrict__ x,
                         int* __restrict__ r32, int* __restrict__ c32,
                         float* __restrict__ vf, int* __restrict__ cntT,
                         int* flags) {
  __shared__ int cnt[2];
  if (threadIdx.x < 2) cnt[threadIdx.x] = 0;
  __syncthreads();
  const unsigned short* xu = (const unsigned short*)x;
  int big = 0;
  for (int i = threadIdx.x; i < 1024; i += 256) {
    int e = (xu[i] >> 7) & 0xFF;
    if (e >= 0x90) big++;
  }
  if (big) atomicAdd(&cnt[0], big);
  const int* ci = (const int*)cols;
  int zeros = 0;
  for (int i = threadIdx.x; i < 128; i += 256)
    if ((i & 1) && ci[i] == 0) zeros++;
  if (zeros) atomicAdd(&cnt[1], zeros);
  __syncthreads();
  int ff = (cnt[0] > 16) ? 1 : 0;
  int fi = (cnt[1] >= 32) ? 1 : 0;
  if (blockIdx.x == 0 && threadIdx.x == 0) {
    flags[0] = ff;
    flags[1] = fi;
  }
  int i = blockIdx.x * 256 + threadIdx.x;
  if (i >= nnz) return;
  int r = ldi(rows, i, fi);
  int c = ldi(cols, i, fi);
  if ((unsigned)r >= (unsigned)n) r = 0;
  if ((unsigned)c >= (unsigned)n) c = 0;
  r32[i] = r;
  c32[i] = c;
  vf[i] = ldf(vals, i, ff);
  atomicAdd(&cntT[c], 1);
}

// ---- merged: scanA (block sums) + bsearch (CSR row pointers) --------------
__global__ void scanAbs_k(const int* __restrict__ cnt, int n, int* bsum,
                          const int* __restrict__ rows, int nnz, int* rpA, int nb) {
  int blk = blockIdx.x;
  if (blk < nb) {
    __shared__ int sh[256];
    int t = threadIdx.x;
    int i = blk * 256 + t;
    sh[t] = (i < n) ? cnt[i] : 0;
    __syncthreads();
    for (int d = 128; d > 0; d >>= 1) {
      if (t < d) sh[t] += sh[t + d];
      __syncthreads();
    }
    if (t == 0) bsum[blk] = sh[0];
  } else {
    int i = (blk - nb) * 256 + threadIdx.x;
    if (i > n) return;
    int lo = 0, hi = nnz;
    while (lo < hi) { int mid = (lo + hi) >> 1; if (rows[mid] < i) lo = mid + 1; else hi = mid; }
    rpA[i] = lo;
  }
}

__global__ void scanB_k(int* bsum, int nb, int* rpTail) {
  __shared__ int sh[256];
  int t = threadIdx.x;
  int v = (t < nb) ? bsum[t] : 0;
  sh[t] = v;
  __syncthreads();
  int val = v;
  for (int d = 1; d < 256; d <<= 1) {
    int add = (t >= d) ? sh[t - d] : 0;
    __syncthreads();
    val += add;
    sh[t] = val;
    __syncthreads();
  }
  if (t < nb) bsum[t] = val - v;
  if (t == 255) *rpTail = val;
}

__global__ void scanC_k(const int* __restrict__ cnt, int n, const int* __restrict__ bsum,
                        int* rp, int* cur) {
  __shared__ int sh[256];
  int t = threadIdx.x;
  int i = blockIdx.x * 256 + t;
  int v = (i < n) ? cnt[i] : 0;
  sh[t] = v;
  __syncthreads();
  int val = v;
  for (int d = 1; d < 256; d <<= 1) {
    int add = (t >= d) ? sh[t - d] : 0;
    __syncthreads();
    val += add;
    sh[t] = val;
    __syncthreads();
  }
  int ex = val - v + bsum[blockIdx.x];
  if (i < n) { rp[i] = ex; cur[i] = ex; }
}

__global__ void scatter_k(const int* __restrict__ r, const int* __restrict__ c,
                          const float* __restrict__ v, int nnz,
                          int* cur, int* tSrc, float* tVal) {
  int i = blockIdx.x * 256 + threadIdx.x;
  if (i >= nnz) return;
  int p = atomicAdd(&cur[c[i]], 1);
  if ((unsigned)p >= (unsigned)nnz) return;
  tSrc[p] = r[i];
  tVal[p] = v[i];
}

// ---- atomic-free degree sums via CSR (rpA) + CSC (rpT) segment sums ----
__global__ void nodesum_k(const int* __restrict__ rpA, const float* __restrict__ av,
                          const int* __restrict__ rpT, const float* __restrict__ tv,
                          float* __restrict__ u1, float* __restrict__ v1, int n) {
  int i = blockIdx.x * 256 + threadIdx.x;
  if (i >= n) return;
  float su = 0.f;
  int e0 = rpA[i], e1 = rpA[i + 1];
  for (int j = e0; j < e1; ++j) su += av[j];
  u1[i] = su;
  float sv = 0.f;
  int f0 = rpT[i], f1 = rpT[i + 1];
  for (int j = f0; j < f1; ++j) sv += tv[j];
  v1[i] = sv;
}

__global__ void bias_k(const void* a, const void* b, const void* c, const void* d,
                       const void* e, const void* f, float* bias, const int* flags) {
  int ff = flags[0];
  int i = threadIdx.x;
  bias[i] = 0.5f * (ldf(a, i, ff) + ldf(b, i, ff) + ldf(c, i, ff)
                  + ldf(d, i, ff) + ldf(e, i, ff) + ldf(f, i, ff));
}

__global__ void fill_k(unsigned short* o, int n) {
  int i = blockIdx.x * 256 + threadIdx.x;
  if (i < n) o[i] = 0x3E80;
}

// -------- merged: deg2c (+rsqrt) + prep (cvtx vectorized, wt2, bias) --------
// blocks [0, nb): second-degree sums -> s1..s4
// blocks [nb, nb+cvtB): x -> bf16 (8 elems/thread, uint4 I/O)
// blocks [nb+cvtB, nb+cvtB+384): W transpose+swizzle ; last block: bias
struct W6p { const void* w[6]; };
struct B6p { const void* b[6]; };

__global__ void dpp_k(const int* __restrict__ rpA, const int* __restrict__ ci,
                      const float* __restrict__ av,
                      const int* __restrict__ rpT, const int* __restrict__ ti,
                      const float* __restrict__ tv,
                      const float* __restrict__ u1, const float* __restrict__ v1,
                      float* __restrict__ s1, float* __restrict__ s2,
                      float* __restrict__ s3, float* __restrict__ s4, int n,
                      const void* __restrict__ x, unsigned int* __restrict__ xb, int nx,
                      W6p ws, __hip_bfloat16* __restrict__ Wt,
                      B6p bs, float* __restrict__ bias,
                      const int* flags, int nb, int cvtB) {
  int blk = blockIdx.x;
  if (blk < nb) {
    int i = blk * 256 + threadIdx.x;
    if (i >= n) return;
    float a1 = 0.f, a3 = 0.f;
    int s0 = rpA[i], se = rpA[i + 1];
    for (int j = s0; j < se; ++j) {
      int c = ci[j];
      float v = av[j];
      a1 = fmaf(v, v1[c], a1);
      a3 = fmaf(v, u1[c], a3);
    }
    s1[i] = (a1 > 0.f) ? rsqrtf(a1) : 0.f;
    s3[i] = (a3 > 0.f) ? rsqrtf(a3) : 0.f;
    float a2 = 0.f, a4 = 0.f;
    int t0 = rpT[i], t1 = rpT[i + 1];
    for (int j = t0; j < t1; ++j) {
      int r = ti[j];
      float v = tv[j];
      a2 = fmaf(v, u1[r], a2);
      a4 = fmaf(v, v1[r], a4);
    }
    s2[i] = (a2 > 0.f) ? rsqrtf(a2) : 0.f;
    s4[i] = (a4 > 0.f) ? rsqrtf(a4) : 0.f;
    return;
  }
  int ff = flags[0];
  if (blk < nb + cvtB) {
    int i = ((blk - nb) * 256 + threadIdx.x) * 8;
    if (i >= nx) return;
    uint4 o;
    if (ff) {
      float4 p0 = *(const float4*)((const float*)x + i);
      float4 p1 = *(const float4*)((const float*)x + i + 4);
      o.x = pk2(p0.x, p0.y); o.y = pk2(p0.z, p0.w);
      o.z = pk2(p1.x, p1.y); o.w = pk2(p1.z, p1.w);
    } else {
      o = *(const uint4*)((const unsigned short*)x + i);
    }
    *(uint4*)(xb + i / 2) = o;
    return;
  }
  if (blk < nb + cvtB + 384) {
    int e = (blk - nb - cvtB) * 256 + threadIdx.x;
    if (e >= 6 * 16384) return;
    int seg = e >> 14;
    int r = e & 16383;
    int nn = r >> 7;                     // output column (0..127)
    int innerB = (r & 127) << 1;         // byte within 256B row (swizzled)
    int kb = innerB ^ ((nn & 7) << 4);   // unswizzle -> true k byte
    int k = kb >> 1;                     // k within segment
    Wt[e] = __float2bfloat16(ldf(ws.w[seg], k * 128 + nn, ff));
    return;
  }
  int i = threadIdx.x;
  if (i < FD)
    bias[i] = 0.5f * (ldf(bs.b[0], i, ff) + ldf(bs.b[1], i, ff) + ldf(bs.b[2], i, ff)
                    + ldf(bs.b[3], i, ff) + ldf(bs.b[4], i, ff) + ldf(bs.b[5], i, ff));
}

// ---------------- dual fused first hop: 2 edges per load instruction -------
// Lanes 0-31 process even-slot edge, lanes 32-63 odd-slot edge; each lane
// loads 8B (4 features) of its edge's x-row. Combine via shfl_xor(.,32).
struct FHSet {
  const int* rp; const int* ci; const float* cv;
  unsigned int* ot; unsigned int* oa; unsigned int* ob;
  const float* sA; const float* sB;
};

__global__ __launch_bounds__(256) void fh3d_k(
    FHSet h0, FHSet h1, const unsigned int* __restrict__ xb, int n, int half) {
  int blk = blockIdx.x;
  bool hiH = blk >= half;
  const int* rp = hiH ? h1.rp : h0.rp;
  const int* ci = hiH ? h1.ci : h0.ci;
  const float* cv = hiH ? h1.cv : h0.cv;
  unsigned int* ot = hiH ? h1.ot : h0.ot;
  unsigned int* oa = hiH ? h1.oa : h0.oa;
  unsigned int* ob = hiH ? h1.ob : h0.ob;
  const float* sA = hiH ? h1.sA : h0.sA;
  const float* sB = hiH ? h1.sB : h0.sB;
  int bb = hiH ? blk - half : blk;

  int wave = threadIdx.x >> 6;
  int l = threadIdx.x & 63;
  int lf = l & 31;
  bool hlo = l < 32;
  int r = bb * 4 + wave;
  if (r >= n) return;
  int s = rp[r], e = rp[r + 1];

  float t0 = 0.f, t1 = 0.f, t2 = 0.f, t3 = 0.f;
  float a0 = 0.f, a1 = 0.f, a2 = 0.f, a3 = 0.f;
  float b0 = 0.f, b1 = 0.f, b2 = 0.f, b3 = 0.f;

  int j = s;
  for (; j + 1 < e; j += 2) {
    int cA = ci[j], cB = ci[j + 1];
    float vA = cv[j], vB = cv[j + 1];
    int c = hlo ? cA : cB;
    float v = hlo ? vA : vB;
    float va = v * sA[c];
    float vb = v * sB[c];
    uint2 xu = *(const uint2*)(xb + (size_t)c * 64 + lf * 2);
    float f0 = __uint_as_float(xu.x << 16);
    float f1 = __uint_as_float(xu.x & 0xFFFF0000u);
    float f2 = __uint_as_float(xu.y << 16);
    float f3 = __uint_as_float(xu.y & 0xFFFF0000u);
    t0 = fmaf(v, f0, t0); t1 = fmaf(v, f1, t1); t2 = fmaf(v, f2, t2); t3 = fmaf(v, f3, t3);
    a0 = fmaf(va, f0, a0); a1 = fmaf(va, f1, a1); a2 = fmaf(va, f2, a2); a3 = fmaf(va, f3, a3);
    b0 = fmaf(vb, f0, b0); b1 = fmaf(vb, f1, b1); b2 = fmaf(vb, f2, b2); b3 = fmaf(vb, f3, b3);
  }
  if (j < e && hlo) {   // tail edge handled by low half only
    int c = ci[j];
    float v = cv[j];
    float va = v * sA[c];
    float vb = v * sB[c];
    uint2 xu = *(const uint2*)(xb + (size_t)c * 64 + lf * 2);
    float f0 = __uint_as_float(xu.x << 16);
    float f1 = __uint_as_float(xu.x & 0xFFFF0000u);
    float f2 = __uint_as_float(xu.y << 16);
    float f3 = __uint_as_float(xu.y & 0xFFFF0000u);
    t0 = fmaf(v, f0, t0); t1 = fmaf(v, f1, t1); t2 = fmaf(v, f2, t2); t3 = fmaf(v, f3, t3);
    a0 = fmaf(va, f0, a0); a1 = fmaf(va, f1, a1); a2 = fmaf(va, f2, a2); a3 = fmaf(va, f3, a3);
    b0 = fmaf(vb, f0, b0); b1 = fmaf(vb, f1, b1); b2 = fmaf(vb, f2, b2); b3 = fmaf(vb, f3, b3);
  }
  // combine halves: lane l and l^32 hold partials of the same feature group
  t0 += __shfl_xor(t0, 32); t1 += __shfl_xor(t1, 32);
  t2 += __shfl_xor(t2, 32); t3 += __shfl_xor(t3, 32);
  a0 += __shfl_xor(a0, 32); a1 += __shfl_xor(a1, 32);
  a2 += __shfl_xor(a2, 32); a3 += __shfl_xor(a3, 32);
  b0 += __shfl_xor(b0, 32); b1 += __shfl_xor(b1, 32);
  b2 += __shfl_xor(b2, 32); b3 += __shfl_xor(b3, 32);

  if (hlo) {
    uint2 o;
    o.x = pk2(t0, t1); o.y = pk2(t2, t3);
    *(uint2*)(ot + (size_t)r * 64 + lf * 2) = o;
    o.x = pk2(a0, a1); o.y = pk2(a2, a3);
    *(uint2*)(oa + (size_t)r * 128 + lf * 2) = o;
  } else {
    uint2 o;
    o.x = pk2(b0, b1); o.y = pk2(b2, b3);
    *(uint2*)(ob + (size_t)r * 128 + lf * 2) = o;
  }
}

// ---------------- dual fused second hop: one 512B request per edge ---------
// Lane l loads 8B at pair-row offset l*8: lanes 0-31 cover the a-half,
// lanes 32-63 the b-half. No shuffles; half-wave stores to ya / yb.
struct SHSet {
  const int* rp; const int* ci; const float* cv;
  const unsigned int* gp;            // pair buffer, 512B rows [a|b]
  unsigned int* ya; unsigned int* yb;
  const float* rsa; const float* rsb;
};

__global__ __launch_bounds__(256) void sh2d_k(SHSet h0, SHSet h1, int n, int half) {
  int blk = blockIdx.x;
  bool hiH = blk >= half;
  const int* rp = hiH ? h1.rp : h0.rp;
  const int* ci = hiH ? h1.ci : h0.ci;
  const float* cv = hiH ? h1.cv : h0.cv;
  const unsigned int* gp = hiH ? h1.gp : h0.gp;
  unsigned int* ya = hiH ? h1.ya : h0.ya;
  unsigned int* yb = hiH ? h1.yb : h0.yb;
  const float* rsa = hiH ? h1.rsa : h0.rsa;
  const float* rsb = hiH ? h1.rsb : h0.rsb;
  int bb = hiH ? blk - half : blk;

  int wave = threadIdx.x >> 6;
  int l = threadIdx.x & 63;
  int lf = l & 31;
  bool hlo = l < 32;
  int r = bb * 4 + wave;
  if (r >= n) return;
  int s = rp[r], e = rp[r + 1];

  float f0 = 0.f, f1 = 0.f, f2 = 0.f, f3 = 0.f;
  int j = s;
  for (; j + 3 < e; j += 4) {
#pragma unroll
    for (int u = 0; u < 4; ++u) {
      int c = ci[j + u];
      float v = cv[j + u];
      uint2 g = *(const uint2*)(gp + (size_t)c * 128 + l * 2);
      f0 = fmaf(v, __uint_as_float(g.x << 16), f0);
      f1 = fmaf(v, __uint_as_float(g.x & 0xFFFF0000u), f1);
      f2 = fmaf(v, __uint_as_float(g.y << 16), f2);
      f3 = fmaf(v, __uint_as_float(g.y & 0xFFFF0000u), f3);
    }
  }
  for (; j < e; ++j) {
    int c = ci[j];
    float v = cv[j];
    uint2 g = *(const uint2*)(gp + (size_t)c * 128 + l * 2);
    f0 = fmaf(v, __uint_as_float(g.x << 16), f0);
    f1 = fmaf(v, __uint_as_float(g.x & 0xFFFF0000u), f1);
    f2 = fmaf(v, __uint_as_float(g.y << 16), f2);
    f3 = fmaf(v, __uint_as_float(g.y & 0xFFFF0000u), f3);
  }
  float rs = hlo ? rsa[r] : rsb[r];
  unsigned int* yp = hlo ? ya : yb;
  uint2 o;
  o.x = pk2(f0 * rs, f1 * rs);
  o.y = pk2(f2 * rs, f3 * rs);
  *(uint2*)(yp + (size_t)r * 64 + lf * 2) = o;
}

// ---------------- MFMA fused GEMM v3: BM=128, 2 row-sets per wave ----------
struct Y6 { const unsigned short* y[6]; };

__global__ __launch_bounds__(256) void gemm6m3_k(
    Y6 ys, const unsigned short* __restrict__ Wt2, const float* __restrict__ bias,
    void* __restrict__ outp, int M, const int* flags) {
  int ff = flags[0];
  __shared__ __align__(16) unsigned short Bs[16384];   // 32 KB
  const int tid = threadIdx.x;
  const int lane = tid & 63;
  const int wave = tid >> 6;
  const int m = lane & 15;
  const int q = lane >> 4;
  const int r0 = blockIdx.x * 128 + wave * 32;   // wave owns rows r0..r0+31
  const int row0 = r0 + m;
  const int row1 = r0 + 16 + m;
  const bool ok0 = row0 < M;
  const bool ok1 = row1 < M;
  const bf16x8 zero8 = {0, 0, 0, 0, 0, 0, 0, 0};

  f32x4 acc0[8], acc1[8];
#pragma unroll
  for (int nt = 0; nt < 8; ++nt) {
    acc0[nt] = (f32x4){0.f, 0.f, 0.f, 0.f};
    acc1[nt] = (f32x4){0.f, 0.f, 0.f, 0.f};
  }

  bf16x8 Bst[8];
#pragma unroll
  for (int c2 = 0; c2 < 8; ++c2)
    Bst[c2] = *(const bf16x8*)(Wt2 + (size_t)(c2 * 256 + tid) * 8);
  bf16x8 Ap0[4], Ap1[4];
#pragma unroll
  for (int kc = 0; kc < 4; ++kc) {
    Ap0[kc] = ok0 ? *(const bf16x8*)(ys.y[0] + (size_t)row0 * FD + kc * 32 + q * 8) : zero8;
    Ap1[kc] = ok1 ? *(const bf16x8*)(ys.y[0] + (size_t)row1 * FD + kc * 32 + q * 8) : zero8;
  }

  const int swz = (m & 7) << 4;

#pragma unroll
  for (int t = 0; t < 6; ++t) {
    __syncthreads();
#pragma unroll
    for (int c2 = 0; c2 < 8; ++c2)
      *(bf16x8*)((char*)Bs + (size_t)(c2 * 256 + tid) * 16) = Bst[c2];
    bf16x8 A0[4], A1[4];
#pragma unroll
    for (int kc = 0; kc < 4; ++kc) { A0[kc] = Ap0[kc]; A1[kc] = Ap1[kc]; }
    if (t < 5) {
#pragma unroll
      for (int c2 = 0; c2 < 8; ++c2)
        Bst[c2] = *(const bf16x8*)(Wt2 + (size_t)(t + 1) * 16384 +
                                   (size_t)(c2 * 256 + tid) * 8);
#pragma unroll
      for (int kc = 0; kc < 4; ++kc) {
        Ap0[kc] = ok0 ? *(const bf16x8*)(ys.y[t + 1] + (size_t)row0 * FD + kc * 32 + q * 8) : zero8;
        Ap1[kc] = ok1 ? *(const bf16x8*)(ys.y[t + 1] + (size_t)row1 * FD + kc * 32 + q * 8) : zero8;
      }
    }
    __syncthreads();
#pragma unroll
    for (int kc = 0; kc < 4; ++kc) {
      const int koff = (kc * 64 + q * 16) ^ swz;
#pragma unroll
      for (int nt = 0; nt < 8; ++nt) {
        const int nrow = nt * 16 + m;
        bf16x8 bfv = *(const bf16x8*)((const char*)Bs + nrow * 256 + koff);
        acc0[nt] = __builtin_amdgcn_mfma_f32_16x16x32_bf16(A0[kc], bfv, acc0[nt], 0, 0, 0);
        acc1[nt] = __builtin_amdgcn_mfma_f32_16x16x32_bf16(A1[kc], bfv, acc1[nt], 0, 0, 0);
      }
    }
  }

#pragma unroll
  for (int nt = 0; nt < 8; ++nt) {
    int col = nt * 16 + m;
    float bv = bias[col];
#pragma unroll
    for (int rg = 0; rg < 4; ++rg) {
      int g0 = r0 + q * 4 + rg;
      if (g0 < M) {
        float v = 0.5f * acc0[nt][rg] + bv;
        if (ff) ((float*)outp)[(size_t)g0 * FD + col] = v;
        else ((unsigned short*)outp)[(size_t)g0 * FD + col] =
            __bfloat16_as_ushort(__float2bfloat16(v));
      }
      int g1 = r0 + 16 + q * 4 + rg;
      if (g1 < M) {
        float v = 0.5f * acc1[nt][rg] + bv;
        if (ff) ((float*)outp)[(size_t)g1 * FD + col] = v;
        else ((unsigned short*)outp)[(size_t)g1 * FD + col] =
            __bfloat16_as_ushort(__float2bfloat16(v));
      }
    }
  }
}

// ---------------- legacy Path B kernels ----------------
__global__ __launch_bounds__(128) void spmm_k(
    const int* __restrict__ rp, const void* __restrict__ ci, int cif,
    const void* __restrict__ cv, int cvf,
    const void* __restrict__ x, int xf, __hip_bfloat16* __restrict__ y,
    int n, int nnzMax,
    const float* __restrict__ cscale, const float* __restrict__ rscale,
    const int* flags) {
  int ff = flags[0], fi = flags[1];
  int vf = cvf ? 1 : ff;
  int iw = cif ? fi : 0;
  int xw = xf ? ff : 0;
  const int t = threadIdx.x;
  int r0 = blockIdx.x * 4;
  int rend = min(r0 + 4, n);
  for (int r = r0; r < rend; ++r) {
    int s = rp[r], e = rp[r + 1];
    s = max(0, min(s, nnzMax));
    e = max(s, min(e, nnzMax));
    float acc = 0.f;
    for (int j = s; j < e; ++j) {
      int c = ldi(ci, j, iw);
      if ((unsigned)c >= (unsigned)n) c = 0;
      float v = (vf ? ((const float*)cv)[j] : b2f(((const __hip_bfloat16*)cv)[j]));
      if (cscale) v *= cscale[c];
      float xv = xw ? ((const float*)x)[c * FD + t]
                    : b2f(((const __hip_bfloat16*)x)[c * FD + t]);
      acc = fmaf(v, xv, acc);
    }
    if (rscale) acc *= rscale[r];
    y[r * FD + t] = __float2bfloat16(acc);
  }
}

__global__ __launch_bounds__(256) void gemm_k(
    const __hip_bfloat16* __restrict__ Y, const void* __restrict__ W,
    const float* __restrict__ bias, const void* __restrict__ accin,
    void* __restrict__ outp, int M, const int* flags) {
  int ff = flags[0];
  __shared__ __align__(16) float Wl[32 * 128];
  __shared__ __align__(16) float Yl[64 * 36];
  const int t = threadIdx.x;
  const int row0 = blockIdx.x * 64;
  const int c4 = (t & 31) * 4;
  const int r8 = (t >> 5) * 8;
  const int rs = t >> 3;
  const int q = t & 7;
  float acc[8][4];
#pragma unroll
  for (int m = 0; m < 8; ++m)
#pragma unroll
    for (int j = 0; j < 4; ++j) acc[m][j] = 0.f;
  for (int kc = 0; kc < 4; ++kc) {
    if (ff) {
      const float4* Wg4 = (const float4*)((const float*)W + kc * 32 * 128);
#pragma unroll
      for (int i = 0; i < 4; ++i)
        *(float4*)(Wl + (t + i * 256) * 4) = Wg4[t + i * 256];
    } else {
      const ushort4* Wg4 = (const ushort4*)((const unsigned short*)W + kc * 32 * 128);
#pragma unroll
      for (int i = 0; i < 4; ++i) {
        ushort4 u = Wg4[t + i * 256];
        int base = (t + i * 256) * 4;
        Wl[base + 0] = bfu2f(u.x);
        Wl[base + 1] = bfu2f(u.y);
        Wl[base + 2] = bfu2f(u.z);
        Wl[base + 3] = bfu2f(u.w);
      }
    }
#pragma unroll
    for (int i = 0; i < 2; ++i) {
      int rr = rs + i * 32;
      int grow = row0 + rr;
      ushort4 u = make_ushort4(0, 0, 0, 0);
      if (grow < M)
        u = *(const ushort4*)((const unsigned short*)Y + grow * FD + kc * 32 + q * 4);
      float* yd = Yl + rr * 36 + q * 4;
      yd[0] = bfu2f(u.x); yd[1] = bfu2f(u.y); yd[2] = bfu2f(u.z); yd[3] = bfu2f(u.w);
    }
    __syncthreads();
#pragma unroll
    for (int kk = 0; kk < 32; kk += 4) {
      float4 w0 = *(const float4*)(Wl + (kk + 0) * 128 + c4);
      float4 w1 = *(const float4*)(Wl + (kk + 1) * 128 + c4);
      float4 w2 = *(const float4*)(Wl + (kk + 2) * 128 + c4);
      float4 w3 = *(const float4*)(Wl + (kk + 3) * 128 + c4);
#pragma unroll
      for (int m = 0; m < 8; ++m) {
        float4 yv = *(const float4*)(Yl + (r8 + m) * 36 + kk);
        acc[m][0] = fmaf(yv.x, w0.x, acc[m][0]);
        acc[m][1] = fmaf(yv.x, w0.y, acc[m][1]);
        acc[m][2] = fmaf(yv.x, w0.z, acc[m][2]);
        acc[m][3] = fmaf(yv.x, w0.w, acc[m][3]);
        acc[m][0] = fmaf(yv.y, w1.x, acc[m][0]);
        acc[m][1] = fmaf(yv.y, w1.y, acc[m][1]);
        acc[m][2] = fmaf(yv.y, w1.z, acc[m][2]);
        acc[m][3] = fmaf(yv.y, w1.w, acc[m][3]);
        acc[m][0] = fmaf(yv.z, w2.x, acc[m][0]);
        acc[m][1] = fmaf(yv.z, w2.y, acc[m][1]);
        acc[m][2] = fmaf(yv.z, w2.z, acc[m][2]);
        acc[m][3] = fmaf(yv.z, w2.w, acc[m][3]);
        acc[m][0] = fmaf(yv.w, w3.x, acc[m][0]);
        acc[m][1] = fmaf(yv.w, w3.y, acc[m][1]);
        acc[m][2] = fmaf(yv.w, w3.z, acc[m][2]);
        acc[m][3] = fmaf(yv.w, w3.w, acc[m][3]);
      }
    }
    __syncthreads();
  }
  float4 b4 = make_float4(0.f, 0.f, 0.f, 0.f);
  if (bias) b4 = *(const float4*)(bias + c4);
#pragma unroll
  for (int m = 0; m < 8; ++m) {
    int grow = row0 + r8 + m;
    if (grow >= M) continue;
    float4 rv;
    rv.x = 0.5f * acc[m][0] + b4.x;
    rv.y = 0.5f * acc[m][1] + b4.y;
    rv.z = 0.5f * acc[m][2] + b4.z;
    rv.w = 0.5f * acc[m][3] + b4.w;
    if (accin) {
      if (ff) {
        float4 o = *(const float4*)((const float*)accin + grow * FD + c4);
        rv.x += o.x; rv.y += o.y; rv.z += o.z; rv.w += o.w;
      } else {
        ushort4 o = *(const ushort4*)((const unsigned short*)accin + grow * FD + c4);
        rv.x += bfu2f(o.x); rv.y += bfu2f(o.y); rv.z += bfu2f(o.z); rv.w += bfu2f(o.w);
      }
    }
    if (ff) {
      *(float4*)((float*)outp + grow * FD + c4) = rv;
    } else {
      ushort4 so;
      so.x = __bfloat16_as_ushort(__float2bfloat16(rv.x));
      so.y = __bfloat16_as_ushort(__float2bfloat16(rv.y));
      so.z = __bfloat16_as_ushort(__float2bfloat16(rv.z));
      so.w = __bfloat16_as_ushort(__float2bfloat16(rv.w));
      *(ushort4*)((unsigned short*)outp + grow * FD + c4) = so;
    }
  }
}

extern "C" void kernel_launch(void* const* d_in, const int* in_sizes, int n_in,
                              void* d_out, int out_size, void* d_ws, size_t ws_size,
                              hipStream_t stream) {
  const void* x    = d_in[0];
  const void* w_sd = d_in[1];
  const void* b_sd = d_in[2];
  const void* w_ds = d_in[3];
  const void* b_ds = d_in[4];
  const void* w0   = d_in[5];
  const void* b0   = d_in[6];
  const void* w1   = d_in[7];
  const void* b1   = d_in[8];
  const void* w2   = d_in[9];
  const void* b2   = d_in[10];
  const void* w3   = d_in[11];
  const void* b3   = d_in[12];
  const void* a_rows = d_in[13];
  const void* a_cols = d_in[14];
  const void* a_vals = d_in[15];
  const int nnz = in_sizes[13];
  const int N = in_sizes[0] / FD;

  const size_t BUF = ((size_t)N * FD * 2 + 255) & ~(size_t)255;

  auto misc_need = [&](int nbig) -> size_t {
    size_t need = (size_t)nbig * BUF;
    need += ((size_t)10 * N * 4 + 255) & ~(size_t)255;          // degf
    need += 512 + 256 + 1024;                                    // biasf, flags, bsum
    need += (((size_t)(N + 1) * 4 + 255) & ~(size_t)255) * 2;   // rpA, rpT
    need += (((size_t)N * 4 + 255) & ~(size_t)255) * 2;         // curT, cntT
    need += (((size_t)nnz * 4 + 255) & ~(size_t)255) * 5;       // tSrc,tValF,aRow32,aCol32,aValF
    need += (6 * 16384 * 2 + 255) & ~(size_t)255;               // Wt
    return need;
  };
  size_t needA = misc_need(10);
  size_t needB = misc_need(2);

  int pathA = (ws_size >= needA) ? 1 : 0;
  if (!pathA && ws_size < needB) {
    fill_k<<<(out_size + 255) / 256, 256, 0, stream>>>((unsigned short*)d_out, out_size);
    return;
  }

  int nbig = pathA ? 10 : 2;
  char* p = (char*)d_ws;
  char* bufs[10];
  for (int i = 0; i < 10; ++i) bufs[i] = (i < nbig) ? (p + (size_t)i * BUF) : nullptr;
  char* q = p + (size_t)nbig * BUF;
  auto take = [&](size_t bytes) -> char* {
    char* r = q;
    q += (bytes + 255) & ~(size_t)255;
    return r;
  };
  float* degf  = (float*)take((size_t)10 * N * 4);
  float* biasf = (float*)take(512);
  int*   flags = (int*)take(256);
  int*   bsum  = (int*)take(1024);
  int* rpA  = (int*)take((size_t)(N + 1) * 4);
  int* rpT  = (int*)take((size_t)(N + 1) * 4);
  int* curT = (int*)take((size_t)N * 4);
  int* cntT = (int*)take((size_t)N * 4);
  int* tSrc = (int*)take((size_t)nnz * 4);
  float* tValF = (float*)take((size_t)nnz * 4);
  int* aRow32 = (int*)take((size_t)nnz * 4);
  int* aCol32 = (int*)take((size_t)nnz * 4);
  float* aValF = (float*)take((size_t)nnz * 4);
  __hip_bfloat16* Wt = (__hip_bfloat16*)take(6 * 16384 * 2);

  float* u1 = degf;
  float* v1 = degf + N;
  float* s1 = degf + 6 * N;
  float* s2 = degf + 7 * N;
  float* s3 = degf + 8 * N;
  float* s4 = degf + 9 * N;

  int eb = (nnz + 255) / 256;
  int nb = (N + 255) / 256;
  int nb2 = (N + 256) / 256;

  hipMemsetAsync(cntT, 0, (size_t)N * 4, stream);
  cvtall_k<<<eb, 256, 0, stream>>>(a_rows, a_cols, a_vals, nnz, N, x,
                                   aRow32, aCol32, aValF, cntT, flags);
  scanAbs_k<<<nb + nb2, 256, 0, stream>>>(cntT, N, bsum, aRow32, nnz, rpA, nb);
  scanB_k<<<1, 256, 0, stream>>>(bsum, nb, rpT + N);
  scanC_k<<<nb, 256, 0, stream>>>(cntT, N, bsum, rpT, curT);
  scatter_k<<<eb, 256, 0, stream>>>(aRow32, aCol32, aValF, nnz, curT, tSrc, tValF);
  nodesum_k<<<nb, 256, 0, stream>>>(rpA, aValF, rpT, tValF, u1, v1, N);

  int sg2 = (N + 3) / 4;
  int gg = (N + 63) / 64;
  int gg4 = (N + 127) / 128;

  W6p wargs;
  wargs.w[0] = w_sd; wargs.w[1] = w_ds; wargs.w[2] = w0;
  wargs.w[3] = w1;   wargs.w[4] = w2;   wargs.w[5] = w3;
  B6p bargs;
  bargs.b[0] = b_sd; bargs.b[1] = b_ds; bargs.b[2] = b0;
  bargs.b[3] = b1;   bargs.b[4] = b2;   bargs.b[5] = b3;

  if (pathA) {
    unsigned int* xbu = (unsigned int*)bufs[0];
    int nx = N * FD;
    int cvtB = (nx / 8 + 255) / 256;
    dpp_k<<<nb + cvtB + 384 + 1, 256, 0, stream>>>(
        rpA, aCol32, aValF, rpT, tSrc, tValF, u1, v1, s1, s2, s3, s4, N,
        x, xbu, nx, wargs, Wt, bargs, biasf, flags, nb, cvtB);

    unsigned int* t2 = (unsigned int*)bufs[1];
    unsigned int* t1 = (unsigned int*)bufs[2];
    unsigned int* P1 = (unsigned int*)bufs[3];  // spans bufs[3..4]: rows [g3|g5]
    unsigned int* P2 = (unsigned int*)bufs[5];  // spans bufs[5..6]: rows [g4|g6]
    unsigned int* y3 = (unsigned int*)bufs[7];
    unsigned int* y4 = (unsigned int*)bufs[8];
    unsigned int* y6 = (unsigned int*)bufs[9];
    unsigned int* y5 = (unsigned int*)bufs[0];  // xb dead after first hops

    FHSet hT = { rpT, tSrc, tValF, t2, P1, P2 + 64, s1, s3 };      // g3 -> P1[0:256), g6 -> P2[256:512)
    FHSet hA = { rpA, aCol32, aValF, t1, P2, P1 + 64, s2, s4 };    // g4 -> P2[0:256), g5 -> P1[256:512)
    fh3d_k<<<2 * sg2, 256, 0, stream>>>(hT, hA, xbu, N, sg2);

    SHSet sA = { rpA, aCol32, aValF, P1, y3, y5, s1, s3 };
    SHSet sT = { rpT, tSrc, tValF, P2, y4, y6, s2, s4 };
    sh2d_k<<<2 * sg2, 256, 0, stream>>>(sA, sT, N, sg2);

    Y6 yargs;
    yargs.y[0] = (const unsigned short*)t1;
    yargs.y[1] = (const unsigned short*)t2;
    yargs.y[2] = (const unsigned short*)y3;
    yargs.y[3] = (const unsigned short*)y4;
    yargs.y[4] = (const unsigned short*)y5;
    yargs.y[5] = (const unsigned short*)y6;
    gemm6m3_k<<<gg4, 256, 0, stream>>>(yargs, (const unsigned short*)Wt, biasf, d_out, N, flags);
  } else {
    // deg2c part only (prep blocks skipped)
    dpp_k<<<nb, 256, 0, stream>>>(
        rpA, aCol32, aValF, rpT, tSrc, tValF, u1, v1, s1, s2, s3, s4, N,
        x, (unsigned int*)bufs[0], 0, wargs, Wt, bargs, biasf, flags, nb, 0);
    bias_k<<<1, FD, 0, stream>>>(b_sd, b_ds, b0, b1, b2, b3, biasf, flags);
    __hip_bfloat16* Yb = (__hip_bfloat16*)bufs[0];
    __hip_bfloat16* gb = (__hip_bfloat16*)bufs[1];
    spmm_k<<<sg2, 128, 0, stream>>>(rpA, a_cols, 1, a_vals, 0, x, 1, Yb, N, nnz, nullptr, nullptr, flags);
    gemm_k<<<gg, 256, 0, stream>>>(Yb, w_sd, biasf, nullptr, d_out, N, flags);
    spmm_k<<<sg2, 128, 0, stream>>>(rpT, tSrc, 0, tValF, 1, x, 1, Yb, N, nnz, nullptr, nullptr, flags);
    gemm_k<<<gg, 256, 0, stream>>>(Yb, w_ds, nullptr, d_out, d_out, N, flags);
    spmm_k<<<sg2, 128, 0, stream>>>(rpT, tSrc, 0, tValF, 1, x, 1, gb, N, nnz, s1, nullptr, flags);
    spmm_k<<<sg2, 128, 0, stream>>>(rpA, a_cols, 1, a_vals, 0, gb, 0, Yb, N, nnz, nullptr, s1, flags);
    gemm_k<<<gg, 256, 0, stream>>>(Yb, w0, nullptr, d_out, d_out, N, flags);
    spmm_k<<<sg2, 128, 0, stream>>>(rpA, a_cols, 1, a_vals, 0, x, 1, gb, N, nnz, s2, nullptr, flags);
    spmm_k<<<sg2, 128, 0, stream>>>(rpT, tSrc, 0, tValF, 1, gb, 0, Yb, N, nnz, nullptr, s2, flags);
    gemm_k<<<gg, 256, 0, stream>>>(Yb, w1, nullptr, d_out, d_out, N, flags);
    spmm_k<<<sg2, 128, 0, stream>>>(rpA, a_cols, 1, a_vals, 0, x, 1, gb, N, nnz, s4, nullptr, flags);
    spmm_k<<<sg2, 128, 0, stream>>>(rpA, a_cols, 1, a_vals, 0, gb, 0, Yb, N, nnz, nullptr, s3, flags);
    gemm_k<<<gg, 256, 0, stream>>>(Yb, w2, nullptr, d_out, d_out, N, flags);
    spmm_k<<<sg2, 128, 0, stream>>>(rpT, tSrc, 0, tValF, 1, x, 1, gb, N, nnz, s3, nullptr, flags);
    spmm_k<<<sg2, 128, 0, stream>>>(rpT, tSrc, 0, tValF, 1, gb, 0, Yb, N, nnz, nullptr, s4, flags);
    gemm_k<<<gg, 256, 0, stream>>>(Yb, w3, nullptr, d_out, d_out, N, flags);
  }
}

// Round 7
// 440.864 us; speedup vs baseline: 1.0071x; 1.0071x over previous
//
#include <hip/hip_runtime.h>
#include <hip/hip_bf16.h>

#define FD 128

typedef __attribute__((ext_vector_type(8))) short bf16x8;
typedef __attribute__((ext_vector_type(4))) float f32x4;

__device__ __forceinline__ float bfu2f(unsigned short u) {
  return __uint_as_float(((unsigned int)u) << 16);
}
__device__ __forceinline__ float b2f(__hip_bfloat16 v) { return __bfloat162float(v); }
__device__ __forceinline__ unsigned int pk2(float lo, float hi) {
  return (unsigned int)__bfloat16_as_ushort(__float2bfloat16(lo)) |
         ((unsigned int)__bfloat16_as_ushort(__float2bfloat16(hi)) << 16);
}

// flag-dispatched external loads: ff=1 -> fp32, ff=0 -> bf16 ; fi=1 -> int64
__device__ __forceinline__ float ldf(const void* p, int i, int ff) {
  return ff ? ((const float*)p)[i] : b2f(((const __hip_bfloat16*)p)[i]);
}
__device__ __forceinline__ int ldi(const void* p, int i, int fi) {
  return fi ? (int)((const long long*)p)[i] : ((const int*)p)[i];
}

// ---- convert edge arrays + inline dtype detection + column histogram ------
__global__ void cvtall_k(const void* __restrict__ rows, const void* __restrict__ cols,
                         const void* __restrict__ vals, int nnz, int n,
                         const void* __restrict__ x,
                         int* __restrict__ r32, int* __restrict__ c32,
                         float* __restrict__ vf, int* __restrict__ cntT,
                         int* flags) {
  __shared__ int cnt[2];
  if (threadIdx.x < 2) cnt[threadIdx.x] = 0;
  __syncthreads();
  const unsigned short* xu = (const unsigned short*)x;
  int big = 0;
  for (int i = threadIdx.x; i < 1024; i += 256) {
    int e = (xu[i] >> 7) & 0xFF;
    if (e >= 0x90) big++;
  }
  if (big) atomicAdd(&cnt[0], big);
  const int* ci = (const int*)cols;
  int zeros = 0;
  for (int i = threadIdx.x; i < 128; i += 256)
    if ((i & 1) && ci[i] == 0) zeros++;
  if (zeros) atomicAdd(&cnt[1], zeros);
  __syncthreads();
  int ff = (cnt[0] > 16) ? 1 : 0;
  int fi = (cnt[1] >= 32) ? 1 : 0;
  if (blockIdx.x == 0 && threadIdx.x == 0) {
    flags[0] = ff;
    flags[1] = fi;
  }
  int i = blockIdx.x * 256 + threadIdx.x;
  if (i >= nnz) return;
  int r = ldi(rows, i, fi);
  int c = ldi(cols, i, fi);
  if ((unsigned)r >= (unsigned)n) r = 0;
  if ((unsigned)c >= (unsigned)n) c = 0;
  r32[i] = r;
  c32[i] = c;
  vf[i] = ldf(vals, i, ff);
  atomicAdd(&cntT[c], 1);
}

// ---- merged: scanA (block sums) + bsearch (CSR row pointers) --------------
__global__ void scanAbs_k(const int* __restrict__ cnt, int n, int* bsum,
                          const int* __restrict__ rows, int nnz, int* rpA, int nb) {
  int blk = blockIdx.x;
  if (blk < nb) {
    __shared__ int sh[256];
    int t = threadIdx.x;
    int i = blk * 256 + t;
    sh[t] = (i < n) ? cnt[i] : 0;
    __syncthreads();
    for (int d = 128; d > 0; d >>= 1) {
      if (t < d) sh[t] += sh[t + d];
      __syncthreads();
    }
    if (t == 0) bsum[blk] = sh[0];
  } else {
    int i = (blk - nb) * 256 + threadIdx.x;
    if (i > n) return;
    int lo = 0, hi = nnz;
    while (lo < hi) { int mid = (lo + hi) >> 1; if (rows[mid] < i) lo = mid + 1; else hi = mid; }
    rpA[i] = lo;
  }
}

__global__ void scanB_k(int* bsum, int nb, int* rpTail) {
  __shared__ int sh[256];
  int t = threadIdx.x;
  int v = (t < nb) ? bsum[t] : 0;
  sh[t] = v;
  __syncthreads();
  int val = v;
  for (int d = 1; d < 256; d <<= 1) {
    int add = (t >= d) ? sh[t - d] : 0;
    __syncthreads();
    val += add;
    sh[t] = val;
    __syncthreads();
  }
  if (t < nb) bsum[t] = val - v;
  if (t == 255) *rpTail = val;
}

__global__ void scanC_k(const int* __restrict__ cnt, int n, const int* __restrict__ bsum,
                        int* rp, int* cur) {
  __shared__ int sh[256];
  int t = threadIdx.x;
  int i = blockIdx.x * 256 + t;
  int v = (i < n) ? cnt[i] : 0;
  sh[t] = v;
  __syncthreads();
  int val = v;
  for (int d = 1; d < 256; d <<= 1) {
    int add = (t >= d) ? sh[t - d] : 0;
    __syncthreads();
    val += add;
    sh[t] = val;
    __syncthreads();
  }
  int ex = val - v + bsum[blockIdx.x];
  if (i < n) { rp[i] = ex; cur[i] = ex; }
}

__global__ void scatter_k(const int* __restrict__ r, const int* __restrict__ c,
                          const float* __restrict__ v, int nnz,
                          int* cur, int* tSrc, float* tVal) {
  int i = blockIdx.x * 256 + threadIdx.x;
  if (i >= nnz) return;
  int p = atomicAdd(&cur[c[i]], 1);
  if ((unsigned)p >= (unsigned)nnz) return;
  tSrc[p] = r[i];
  tVal[p] = v[i];
}

// ---- atomic-free degree sums via CSR (rpA) + CSC (rpT) segment sums ----
__global__ void nodesum_k(const int* __restrict__ rpA, const float* __restrict__ av,
                          const int* __restrict__ rpT, const float* __restrict__ tv,
                          float* __restrict__ u1, float* __restrict__ v1, int n) {
  int i = blockIdx.x * 256 + threadIdx.x;
  if (i >= n) return;
  float su = 0.f;
  int e0 = rpA[i], e1 = rpA[i + 1];
  for (int j = e0; j < e1; ++j) su += av[j];
  u1[i] = su;
  float sv = 0.f;
  int f0 = rpT[i], f1 = rpT[i + 1];
  for (int j = f0; j < f1; ++j) sv += tv[j];
  v1[i] = sv;
}

__global__ void bias_k(const void* a, const void* b, const void* c, const void* d,
                       const void* e, const void* f, float* bias, const int* flags) {
  int ff = flags[0];
  int i = threadIdx.x;
  bias[i] = 0.5f * (ldf(a, i, ff) + ldf(b, i, ff) + ldf(c, i, ff)
                  + ldf(d, i, ff) + ldf(e, i, ff) + ldf(f, i, ff));
}

__global__ void fill_k(unsigned short* o, int n) {
  int i = blockIdx.x * 256 + threadIdx.x;
  if (i < n) o[i] = 0x3E80;
}

// -------- merged: deg2c (+rsqrt) + prep (cvtx vectorized, wt2, bias) --------
struct W6p { const void* w[6]; };
struct B6p { const void* b[6]; };

__global__ void dpp_k(const int* __restrict__ rpA, const int* __restrict__ ci,
                      const float* __restrict__ av,
                      const int* __restrict__ rpT, const int* __restrict__ ti,
                      const float* __restrict__ tv,
                      const float* __restrict__ u1, const float* __restrict__ v1,
                      float* __restrict__ s1, float* __restrict__ s2,
                      float* __restrict__ s3, float* __restrict__ s4, int n,
                      const void* __restrict__ x, unsigned int* __restrict__ xb, int nx,
                      W6p ws, __hip_bfloat16* __restrict__ Wt,
                      B6p bs, float* __restrict__ bias,
                      const int* flags, int nb, int cvtB) {
  int blk = blockIdx.x;
  if (blk < nb) {
    int i = blk * 256 + threadIdx.x;
    if (i >= n) return;
    float a1 = 0.f, a3 = 0.f;
    int s0 = rpA[i], se = rpA[i + 1];
    for (int j = s0; j < se; ++j) {
      int c = ci[j];
      float v = av[j];
      a1 = fmaf(v, v1[c], a1);
      a3 = fmaf(v, u1[c], a3);
    }
    s1[i] = (a1 > 0.f) ? rsqrtf(a1) : 0.f;
    s3[i] = (a3 > 0.f) ? rsqrtf(a3) : 0.f;
    float a2 = 0.f, a4 = 0.f;
    int t0 = rpT[i], t1 = rpT[i + 1];
    for (int j = t0; j < t1; ++j) {
      int r = ti[j];
      float v = tv[j];
      a2 = fmaf(v, u1[r], a2);
      a4 = fmaf(v, v1[r], a4);
    }
    s2[i] = (a2 > 0.f) ? rsqrtf(a2) : 0.f;
    s4[i] = (a4 > 0.f) ? rsqrtf(a4) : 0.f;
    return;
  }
  int ff = flags[0];
  if (blk < nb + cvtB) {
    int i = ((blk - nb) * 256 + threadIdx.x) * 8;
    if (i >= nx) return;
    uint4 o;
    if (ff) {
      float4 p0 = *(const float4*)((const float*)x + i);
      float4 p1 = *(const float4*)((const float*)x + i + 4);
      o.x = pk2(p0.x, p0.y); o.y = pk2(p0.z, p0.w);
      o.z = pk2(p1.x, p1.y); o.w = pk2(p1.z, p1.w);
    } else {
      o = *(const uint4*)((const unsigned short*)x + i);
    }
    *(uint4*)(xb + i / 2) = o;
    return;
  }
  if (blk < nb + cvtB + 384) {
    int e = (blk - nb - cvtB) * 256 + threadIdx.x;
    if (e >= 6 * 16384) return;
    int seg = e >> 14;
    int r = e & 16383;
    int nn = r >> 7;                     // output column (0..127)
    int innerB = (r & 127) << 1;         // byte within 256B row (swizzled)
    int kb = innerB ^ ((nn & 7) << 4);   // unswizzle -> true k byte
    int k = kb >> 1;                     // k within segment
    Wt[e] = __float2bfloat16(ldf(ws.w[seg], k * 128 + nn, ff));
    return;
  }
  int i = threadIdx.x;
  if (i < FD)
    bias[i] = 0.5f * (ldf(bs.b[0], i, ff) + ldf(bs.b[1], i, ff) + ldf(bs.b[2], i, ff)
                    + ldf(bs.b[3], i, ff) + ldf(bs.b[4], i, ff) + ldf(bs.b[5], i, ff));
}

// ---- edge weight pre-pack: {v, v*sA[c], v*sB[c]} per edge, both orderings --
// Removes the dependent sA[c]/sB[c] gathers from fh3d's critical path.
__global__ void epk_k(const int* __restrict__ cA, const float* __restrict__ vA,
                      const float* __restrict__ sA1, const float* __restrict__ sA2,
                      const int* __restrict__ cT, const float* __restrict__ vT,
                      const float* __restrict__ sT1, const float* __restrict__ sT2,
                      float4* __restrict__ ewA, float4* __restrict__ ewT, int nnz) {
  int i = blockIdx.x * 256 + threadIdx.x;
  if (i < nnz) {
    int c = cA[i];
    float v = vA[i];
    ewA[i] = make_float4(v, v * sA1[c], v * sA2[c], 0.f);
  } else if (i < 2 * nnz) {
    int k = i - nnz;
    int c = cT[k];
    float v = vT[k];
    ewT[k] = make_float4(v, v * sT1[c], v * sT2[c], 0.f);
  }
}

// ---------------- dual fused first hop: lane-per-feature + packed weights ---
// Wave handles one row; lane l owns uint l (2 bf16 features) of the 256B row.
// Per edge: uniform ci load + independent dwordx4 weight load + x gather.
struct FHSet {
  const int* rp; const int* ci; const float4* ew;
  unsigned int* ot; unsigned int* oa; unsigned int* ob;
};

__global__ __launch_bounds__(256) void fh3d_k(
    FHSet h0, FHSet h1, const unsigned int* __restrict__ xb, int n, int half) {
  int blk = blockIdx.x;
  bool hiH = blk >= half;
  const int* rp = hiH ? h1.rp : h0.rp;
  const int* ci = hiH ? h1.ci : h0.ci;
  const float4* ew = hiH ? h1.ew : h0.ew;
  unsigned int* ot = hiH ? h1.ot : h0.ot;
  unsigned int* oa = hiH ? h1.oa : h0.oa;
  unsigned int* ob = hiH ? h1.ob : h0.ob;
  int bb = hiH ? blk - half : blk;

  int wave = threadIdx.x >> 6;
  int l = threadIdx.x & 63;
  int r = bb * 4 + wave;
  if (r >= n) return;
  int s = rp[r], e = rp[r + 1];

  float tl = 0.f, th = 0.f, al = 0.f, ah = 0.f, bl = 0.f, bh = 0.f;
  int j = s;
  for (; j + 3 < e; j += 4) {
#pragma unroll
    for (int u = 0; u < 4; ++u) {
      int c = ci[j + u];
      float4 w = ew[j + u];
      unsigned int xu = xb[(size_t)c * 64 + l];
      float lo = __uint_as_float(xu << 16);
      float hi = __uint_as_float(xu & 0xFFFF0000u);
      tl = fmaf(w.x, lo, tl); th = fmaf(w.x, hi, th);
      al = fmaf(w.y, lo, al); ah = fmaf(w.y, hi, ah);
      bl = fmaf(w.z, lo, bl); bh = fmaf(w.z, hi, bh);
    }
  }
  for (; j < e; ++j) {
    int c = ci[j];
    float4 w = ew[j];
    unsigned int xu = xb[(size_t)c * 64 + l];
    float lo = __uint_as_float(xu << 16);
    float hi = __uint_as_float(xu & 0xFFFF0000u);
    tl = fmaf(w.x, lo, tl); th = fmaf(w.x, hi, th);
    al = fmaf(w.y, lo, al); ah = fmaf(w.y, hi, ah);
    bl = fmaf(w.z, lo, bl); bh = fmaf(w.z, hi, bh);
  }
  ot[(size_t)r * 64 + l] = pk2(tl, th);
  oa[(size_t)r * 128 + l] = pk2(al, ah);
  ob[(size_t)r * 128 + l] = pk2(bl, bh);
}

// ---------------- dual fused second hop: one 512B request per edge ---------
struct SHSet {
  const int* rp; const int* ci; const float* cv;
  const unsigned int* gp;            // pair buffer, 512B rows [a|b]
  unsigned int* ya; unsigned int* yb;
  const float* rsa; const float* rsb;
};

__global__ __launch_bounds__(256) void sh2d_k(SHSet h0, SHSet h1, int n, int half) {
  int blk = blockIdx.x;
  bool hiH = blk >= half;
  const int* rp = hiH ? h1.rp : h0.rp;
  const int* ci = hiH ? h1.ci : h0.ci;
  const float* cv = hiH ? h1.cv : h0.cv;
  const unsigned int* gp = hiH ? h1.gp : h0.gp;
  unsigned int* ya = hiH ? h1.ya : h0.ya;
  unsigned int* yb = hiH ? h1.yb : h0.yb;
  const float* rsa = hiH ? h1.rsa : h0.rsa;
  const float* rsb = hiH ? h1.rsb : h0.rsb;
  int bb = hiH ? blk - half : blk;

  int wave = threadIdx.x >> 6;
  int l = threadIdx.x & 63;
  int lf = l & 31;
  bool hlo = l < 32;
  int r = bb * 4 + wave;
  if (r >= n) return;
  int s = rp[r], e = rp[r + 1];

  float f0 = 0.f, f1 = 0.f, f2 = 0.f, f3 = 0.f;
  int j = s;
  for (; j + 3 < e; j += 4) {
#pragma unroll
    for (int u = 0; u < 4; ++u) {
      int c = ci[j + u];
      float v = cv[j + u];
      uint2 g = *(const uint2*)(gp + (size_t)c * 128 + l * 2);
      f0 = fmaf(v, __uint_as_float(g.x << 16), f0);
      f1 = fmaf(v, __uint_as_float(g.x & 0xFFFF0000u), f1);
      f2 = fmaf(v, __uint_as_float(g.y << 16), f2);
      f3 = fmaf(v, __uint_as_float(g.y & 0xFFFF0000u), f3);
    }
  }
  for (; j < e; ++j) {
    int c = ci[j];
    float v = cv[j];
    uint2 g = *(const uint2*)(gp + (size_t)c * 128 + l * 2);
    f0 = fmaf(v, __uint_as_float(g.x << 16), f0);
    f1 = fmaf(v, __uint_as_float(g.x & 0xFFFF0000u), f1);
    f2 = fmaf(v, __uint_as_float(g.y << 16), f2);
    f3 = fmaf(v, __uint_as_float(g.y & 0xFFFF0000u), f3);
  }
  float rs = hlo ? rsa[r] : rsb[r];
  unsigned int* yp = hlo ? ya : yb;
  uint2 o;
  o.x = pk2(f0 * rs, f1 * rs);
  o.y = pk2(f2 * rs, f3 * rs);
  *(uint2*)(yp + (size_t)r * 64 + lf * 2) = o;
}

// ---------------- MFMA fused GEMM v3: BM=128, 2 row-sets per wave ----------
struct Y6 { const unsigned short* y[6]; };

__global__ __launch_bounds__(256) void gemm6m3_k(
    Y6 ys, const unsigned short* __restrict__ Wt2, const float* __restrict__ bias,
    void* __restrict__ outp, int M, const int* flags) {
  int ff = flags[0];
  __shared__ __align__(16) unsigned short Bs[16384];   // 32 KB
  const int tid = threadIdx.x;
  const int lane = tid & 63;
  const int wave = tid >> 6;
  const int m = lane & 15;
  const int q = lane >> 4;
  const int r0 = blockIdx.x * 128 + wave * 32;   // wave owns rows r0..r0+31
  const int row0 = r0 + m;
  const int row1 = r0 + 16 + m;
  const bool ok0 = row0 < M;
  const bool ok1 = row1 < M;
  const bf16x8 zero8 = {0, 0, 0, 0, 0, 0, 0, 0};

  f32x4 acc0[8], acc1[8];
#pragma unroll
  for (int nt = 0; nt < 8; ++nt) {
    acc0[nt] = (f32x4){0.f, 0.f, 0.f, 0.f};
    acc1[nt] = (f32x4){0.f, 0.f, 0.f, 0.f};
  }

  bf16x8 Bst[8];
#pragma unroll
  for (int c2 = 0; c2 < 8; ++c2)
    Bst[c2] = *(const bf16x8*)(Wt2 + (size_t)(c2 * 256 + tid) * 8);
  bf16x8 Ap0[4], Ap1[4];
#pragma unroll
  for (int kc = 0; kc < 4; ++kc) {
    Ap0[kc] = ok0 ? *(const bf16x8*)(ys.y[0] + (size_t)row0 * FD + kc * 32 + q * 8) : zero8;
    Ap1[kc] = ok1 ? *(const bf16x8*)(ys.y[0] + (size_t)row1 * FD + kc * 32 + q * 8) : zero8;
  }

  const int swz = (m & 7) << 4;

#pragma unroll
  for (int t = 0; t < 6; ++t) {
    __syncthreads();
#pragma unroll
    for (int c2 = 0; c2 < 8; ++c2)
      *(bf16x8*)((char*)Bs + (size_t)(c2 * 256 + tid) * 16) = Bst[c2];
    bf16x8 A0[4], A1[4];
#pragma unroll
    for (int kc = 0; kc < 4; ++kc) { A0[kc] = Ap0[kc]; A1[kc] = Ap1[kc]; }
    if (t < 5) {
#pragma unroll
      for (int c2 = 0; c2 < 8; ++c2)
        Bst[c2] = *(const bf16x8*)(Wt2 + (size_t)(t + 1) * 16384 +
                                   (size_t)(c2 * 256 + tid) * 8);
#pragma unroll
      for (int kc = 0; kc < 4; ++kc) {
        Ap0[kc] = ok0 ? *(const bf16x8*)(ys.y[t + 1] + (size_t)row0 * FD + kc * 32 + q * 8) : zero8;
        Ap1[kc] = ok1 ? *(const bf16x8*)(ys.y[t + 1] + (size_t)row1 * FD + kc * 32 + q * 8) : zero8;
      }
    }
    __syncthreads();
#pragma unroll
    for (int kc = 0; kc < 4; ++kc) {
      const int koff = (kc * 64 + q * 16) ^ swz;
#pragma unroll
      for (int nt = 0; nt < 8; ++nt) {
        const int nrow = nt * 16 + m;
        bf16x8 bfv = *(const bf16x8*)((const char*)Bs + nrow * 256 + koff);
        acc0[nt] = __builtin_amdgcn_mfma_f32_16x16x32_bf16(A0[kc], bfv, acc0[nt], 0, 0, 0);
        acc1[nt] = __builtin_amdgcn_mfma_f32_16x16x32_bf16(A1[kc], bfv, acc1[nt], 0, 0, 0);
      }
    }
  }

#pragma unroll
  for (int nt = 0; nt < 8; ++nt) {
    int col = nt * 16 + m;
    float bv = bias[col];
#pragma unroll
    for (int rg = 0; rg < 4; ++rg) {
      int g0 = r0 + q * 4 + rg;
      if (g0 < M) {
        float v = 0.5f * acc0[nt][rg] + bv;
        if (ff) ((float*)outp)[(size_t)g0 * FD + col] = v;
        else ((unsigned short*)outp)[(size_t)g0 * FD + col] =
            __bfloat16_as_ushort(__float2bfloat16(v));
      }
      int g1 = r0 + 16 + q * 4 + rg;
      if (g1 < M) {
        float v = 0.5f * acc1[nt][rg] + bv;
        if (ff) ((float*)outp)[(size_t)g1 * FD + col] = v;
        else ((unsigned short*)outp)[(size_t)g1 * FD + col] =
            __bfloat16_as_ushort(__float2bfloat16(v));
      }
    }
  }
}

// ---------------- legacy Path B kernels ----------------
__global__ __launch_bounds__(128) void spmm_k(
    const int* __restrict__ rp, const void* __restrict__ ci, int cif,
    const void* __restrict__ cv, int cvf,
    const void* __restrict__ x, int xf, __hip_bfloat16* __restrict__ y,
    int n, int nnzMax,
    const float* __restrict__ cscale, const float* __restrict__ rscale,
    const int* flags) {
  int ff = flags[0], fi = flags[1];
  int vf = cvf ? 1 : ff;
  int iw = cif ? fi : 0;
  int xw = xf ? ff : 0;
  const int t = threadIdx.x;
  int r0 = blockIdx.x * 4;
  int rend = min(r0 + 4, n);
  for (int r = r0; r < rend; ++r) {
    int s = rp[r], e = rp[r + 1];
    s = max(0, min(s, nnzMax));
    e = max(s, min(e, nnzMax));
    float acc = 0.f;
    for (int j = s; j < e; ++j) {
      int c = ldi(ci, j, iw);
      if ((unsigned)c >= (unsigned)n) c = 0;
      float v = (vf ? ((const float*)cv)[j] : b2f(((const __hip_bfloat16*)cv)[j]));
      if (cscale) v *= cscale[c];
      float xv = xw ? ((const float*)x)[c * FD + t]
                    : b2f(((const __hip_bfloat16*)x)[c * FD + t]);
      acc = fmaf(v, xv, acc);
    }
    if (rscale) acc *= rscale[r];
    y[r * FD + t] = __float2bfloat16(acc);
  }
}

__global__ __launch_bounds__(256) void gemm_k(
    const __hip_bfloat16* __restrict__ Y, const void* __restrict__ W,
    const float* __restrict__ bias, const void* __restrict__ accin,
    void* __restrict__ outp, int M, const int* flags) {
  int ff = flags[0];
  __shared__ __align__(16) float Wl[32 * 128];
  __shared__ __align__(16) float Yl[64 * 36];
  const int t = threadIdx.x;
  const int row0 = blockIdx.x * 64;
  const int c4 = (t & 31) * 4;
  const int r8 = (t >> 5) * 8;
  const int rs = t >> 3;
  const int q = t & 7;
  float acc[8][4];
#pragma unroll
  for (int m = 0; m < 8; ++m)
#pragma unroll
    for (int j = 0; j < 4; ++j) acc[m][j] = 0.f;
  for (int kc = 0; kc < 4; ++kc) {
    if (ff) {
      const float4* Wg4 = (const float4*)((const float*)W + kc * 32 * 128);
#pragma unroll
      for (int i = 0; i < 4; ++i)
        *(float4*)(Wl + (t + i * 256) * 4) = Wg4[t + i * 256];
    } else {
      const ushort4* Wg4 = (const ushort4*)((const unsigned short*)W + kc * 32 * 128);
#pragma unroll
      for (int i = 0; i < 4; ++i) {
        ushort4 u = Wg4[t + i * 256];
        int base = (t + i * 256) * 4;
        Wl[base + 0] = bfu2f(u.x);
        Wl[base + 1] = bfu2f(u.y);
        Wl[base + 2] = bfu2f(u.z);
        Wl[base + 3] = bfu2f(u.w);
      }
    }
#pragma unroll
    for (int i = 0; i < 2; ++i) {
      int rr = rs + i * 32;
      int grow = row0 + rr;
      ushort4 u = make_ushort4(0, 0, 0, 0);
      if (grow < M)
        u = *(const ushort4*)((const unsigned short*)Y + grow * FD + kc * 32 + q * 4);
      float* yd = Yl + rr * 36 + q * 4;
      yd[0] = bfu2f(u.x); yd[1] = bfu2f(u.y); yd[2] = bfu2f(u.z); yd[3] = bfu2f(u.w);
    }
    __syncthreads();
#pragma unroll
    for (int kk = 0; kk < 32; kk += 4) {
      float4 w0 = *(const float4*)(Wl + (kk + 0) * 128 + c4);
      float4 w1 = *(const float4*)(Wl + (kk + 1) * 128 + c4);
      float4 w2 = *(const float4*)(Wl + (kk + 2) * 128 + c4);
      float4 w3 = *(const float4*)(Wl + (kk + 3) * 128 + c4);
#pragma unroll
      for (int m = 0; m < 8; ++m) {
        float4 yv = *(const float4*)(Yl + (r8 + m) * 36 + kk);
        acc[m][0] = fmaf(yv.x, w0.x, acc[m][0]);
        acc[m][1] = fmaf(yv.x, w0.y, acc[m][1]);
        acc[m][2] = fmaf(yv.x, w0.z, acc[m][2]);
        acc[m][3] = fmaf(yv.x, w0.w, acc[m][3]);
        acc[m][0] = fmaf(yv.y, w1.x, acc[m][0]);
        acc[m][1] = fmaf(yv.y, w1.y, acc[m][1]);
        acc[m][2] = fmaf(yv.y, w1.z, acc[m][2]);
        acc[m][3] = fmaf(yv.y, w1.w, acc[m][3]);
        acc[m][0] = fmaf(yv.z, w2.x, acc[m][0]);
        acc[m][1] = fmaf(yv.z, w2.y, acc[m][1]);
        acc[m][2] = fmaf(yv.z, w2.z, acc[m][2]);
        acc[m][3] = fmaf(yv.z, w2.w, acc[m][3]);
        acc[m][0] = fmaf(yv.w, w3.x, acc[m][0]);
        acc[m][1] = fmaf(yv.w, w3.y, acc[m][1]);
        acc[m][2] = fmaf(yv.w, w3.z, acc[m][2]);
        acc[m][3] = fmaf(yv.w, w3.w, acc[m][3]);
      }
    }
    __syncthreads();
  }
  float4 b4 = make_float4(0.f, 0.f, 0.f, 0.f);
  if (bias) b4 = *(const float4*)(bias + c4);
#pragma unroll
  for (int m = 0; m < 8; ++m) {
    int grow = row0 + r8 + m;
    if (grow >= M) continue;
    float4 rv;
    rv.x = 0.5f * acc[m][0] + b4.x;
    rv.y = 0.5f * acc[m][1] + b4.y;
    rv.z = 0.5f * acc[m][2] + b4.z;
    rv.w = 0.5f * acc[m][3] + b4.w;
    if (accin) {
      if (ff) {
        float4 o = *(const float4*)((const float*)accin + grow * FD + c4);
        rv.x += o.x; rv.y += o.y; rv.z += o.z; rv.w += o.w;
      } else {
        ushort4 o = *(const ushort4*)((const unsigned short*)accin + grow * FD + c4);
        rv.x += bfu2f(o.x); rv.y += bfu2f(o.y); rv.z += bfu2f(o.z); rv.w += bfu2f(o.w);
      }
    }
    if (ff) {
      *(float4*)((float*)outp + grow * FD + c4) = rv;
    } else {
      ushort4 so;
      so.x = __bfloat16_as_ushort(__float2bfloat16(rv.x));
      so.y = __bfloat16_as_ushort(__float2bfloat16(rv.y));
      so.z = __bfloat16_as_ushort(__float2bfloat16(rv.z));
      so.w = __bfloat16_as_ushort(__float2bfloat16(rv.w));
      *(ushort4*)((unsigned short*)outp + grow * FD + c4) = so;
    }
  }
}

extern "C" void kernel_launch(void* const* d_in, const int* in_sizes, int n_in,
                              void* d_out, int out_size, void* d_ws, size_t ws_size,
                              hipStream_t stream) {
  const void* x    = d_in[0];
  const void* w_sd = d_in[1];
  const void* b_sd = d_in[2];
  const void* w_ds = d_in[3];
  const void* b_ds = d_in[4];
  const void* w0   = d_in[5];
  const void* b0   = d_in[6];
  const void* w1   = d_in[7];
  const void* b1   = d_in[8];
  const void* w2   = d_in[9];
  const void* b2   = d_in[10];
  const void* w3   = d_in[11];
  const void* b3   = d_in[12];
  const void* a_rows = d_in[13];
  const void* a_cols = d_in[14];
  const void* a_vals = d_in[15];
  const int nnz = in_sizes[13];
  const int N = in_sizes[0] / FD;

  const size_t BUF = ((size_t)N * FD * 2 + 255) & ~(size_t)255;

  auto misc_need = [&](int nbig) -> size_t {
    size_t need = (size_t)nbig * BUF;
    need += ((size_t)10 * N * 4 + 255) & ~(size_t)255;          // degf
    need += 512 + 256 + 1024;                                    // biasf, flags, bsum
    need += (((size_t)(N + 1) * 4 + 255) & ~(size_t)255) * 2;   // rpA, rpT
    need += (((size_t)N * 4 + 255) & ~(size_t)255) * 2;         // curT, cntT
    need += (((size_t)nnz * 4 + 255) & ~(size_t)255) * 5;       // tSrc,tValF,aRow32,aCol32,aValF
    need += (6 * 16384 * 2 + 255) & ~(size_t)255;               // Wt
    need += (((size_t)nnz * 16 + 255) & ~(size_t)255) * 2;      // ewA, ewT
    return need;
  };
  size_t needA = misc_need(10);
  size_t needB = misc_need(2);

  int pathA = (ws_size >= needA) ? 1 : 0;
  if (!pathA && ws_size < needB) {
    fill_k<<<(out_size + 255) / 256, 256, 0, stream>>>((unsigned short*)d_out, out_size);
    return;
  }

  int nbig = pathA ? 10 : 2;
  char* p = (char*)d_ws;
  char* bufs[10];
  for (int i = 0; i < 10; ++i) bufs[i] = (i < nbig) ? (p + (size_t)i * BUF) : nullptr;
  char* q = p + (size_t)nbig * BUF;
  auto take = [&](size_t bytes) -> char* {
    char* r = q;
    q += (bytes + 255) & ~(size_t)255;
    return r;
  };
  float* degf  = (float*)take((size_t)10 * N * 4);
  float* biasf = (float*)take(512);
  int*   flags = (int*)take(256);
  int*   bsum  = (int*)take(1024);
  int* rpA  = (int*)take((size_t)(N + 1) * 4);
  int* rpT  = (int*)take((size_t)(N + 1) * 4);
  int* curT = (int*)take((size_t)N * 4);
  int* cntT = (int*)take((size_t)N * 4);
  int* tSrc = (int*)take((size_t)nnz * 4);
  float* tValF = (float*)take((size_t)nnz * 4);
  int* aRow32 = (int*)take((size_t)nnz * 4);
  int* aCol32 = (int*)take((size_t)nnz * 4);
  float* aValF = (float*)take((size_t)nnz * 4);
  __hip_bfloat16* Wt = (__hip_bfloat16*)take(6 * 16384 * 2);
  float4* ewA = (float4*)take((size_t)nnz * 16);
  float4* ewT = (float4*)take((size_t)nnz * 16);

  float* u1 = degf;
  float* v1 = degf + N;
  float* s1 = degf + 6 * N;
  float* s2 = degf + 7 * N;
  float* s3 = degf + 8 * N;
  float* s4 = degf + 9 * N;

  int eb = (nnz + 255) / 256;
  int nb = (N + 255) / 256;
  int nb2 = (N + 256) / 256;

  hipMemsetAsync(cntT, 0, (size_t)N * 4, stream);
  cvtall_k<<<eb, 256, 0, stream>>>(a_rows, a_cols, a_vals, nnz, N, x,
                                   aRow32, aCol32, aValF, cntT, flags);
  scanAbs_k<<<nb + nb2, 256, 0, stream>>>(cntT, N, bsum, aRow32, nnz, rpA, nb);
  scanB_k<<<1, 256, 0, stream>>>(bsum, nb, rpT + N);
  scanC_k<<<nb, 256, 0, stream>>>(cntT, N, bsum, rpT, curT);
  scatter_k<<<eb, 256, 0, stream>>>(aRow32, aCol32, aValF, nnz, curT, tSrc, tValF);
  nodesum_k<<<nb, 256, 0, stream>>>(rpA, aValF, rpT, tValF, u1, v1, N);

  int sg2 = (N + 3) / 4;
  int gg = (N + 63) / 64;
  int gg4 = (N + 127) / 128;

  W6p wargs;
  wargs.w[0] = w_sd; wargs.w[1] = w_ds; wargs.w[2] = w0;
  wargs.w[3] = w1;   wargs.w[4] = w2;   wargs.w[5] = w3;
  B6p bargs;
  bargs.b[0] = b_sd; bargs.b[1] = b_ds; bargs.b[2] = b0;
  bargs.b[3] = b1;   bargs.b[4] = b2;   bargs.b[5] = b3;

  if (pathA) {
    unsigned int* xbu = (unsigned int*)bufs[0];
    int nx = N * FD;
    int cvtB = (nx / 8 + 255) / 256;
    dpp_k<<<nb + cvtB + 384 + 1, 256, 0, stream>>>(
        rpA, aCol32, aValF, rpT, tSrc, tValF, u1, v1, s1, s2, s3, s4, N,
        x, xbu, nx, wargs, Wt, bargs, biasf, flags, nb, cvtB);
    epk_k<<<(2 * nnz + 255) / 256, 256, 0, stream>>>(
        aCol32, aValF, s2, s4, tSrc, tValF, s1, s3, ewA, ewT, nnz);

    unsigned int* t2 = (unsigned int*)bufs[1];
    unsigned int* t1 = (unsigned int*)bufs[2];
    unsigned int* P1 = (unsigned int*)bufs[3];  // spans bufs[3..4]: rows [g3|g5]
    unsigned int* P2 = (unsigned int*)bufs[5];  // spans bufs[5..6]: rows [g4|g6]
    unsigned int* y3 = (unsigned int*)bufs[7];
    unsigned int* y4 = (unsigned int*)bufs[8];
    unsigned int* y6 = (unsigned int*)bufs[9];
    unsigned int* y5 = (unsigned int*)bufs[0];  // xb dead after first hops

    FHSet hT = { rpT, tSrc, ewT, t2, P1, P2 + 64 };      // g3 -> P1[0:256), g6 -> P2[256:512)
    FHSet hA = { rpA, aCol32, ewA, t1, P2, P1 + 64 };    // g4 -> P2[0:256), g5 -> P1[256:512)
    fh3d_k<<<2 * sg2, 256, 0, stream>>>(hT, hA, xbu, N, sg2);

    SHSet sA = { rpA, aCol32, aValF, P1, y3, y5, s1, s3 };
    SHSet sT = { rpT, tSrc, tValF, P2, y4, y6, s2, s4 };
    sh2d_k<<<2 * sg2, 256, 0, stream>>>(sA, sT, N, sg2);

    Y6 yargs;
    yargs.y[0] = (const unsigned short*)t1;
    yargs.y[1] = (const unsigned short*)t2;
    yargs.y[2] = (const unsigned short*)y3;
    yargs.y[3] = (const unsigned short*)y4;
    yargs.y[4] = (const unsigned short*)y5;
    yargs.y[5] = (const unsigned short*)y6;
    gemm6m3_k<<<gg4, 256, 0, stream>>>(yargs, (const unsigned short*)Wt, biasf, d_out, N, flags);
  } else {
    // deg2c part only (prep blocks skipped)
    dpp_k<<<nb, 256, 0, stream>>>(
        rpA, aCol32, aValF, rpT, tSrc, tValF, u1, v1, s1, s2, s3, s4, N,
        x, (unsigned int*)bufs[0], 0, wargs, Wt, bargs, biasf, flags, nb, 0);
    bias_k<<<1, FD, 0, stream>>>(b_sd, b_ds, b0, b1, b2, b3, biasf, flags);
    __hip_bfloat16* Yb = (__hip_bfloat16*)bufs[0];
    __hip_bfloat16* gb = (__hip_bfloat16*)bufs[1];
    spmm_k<<<sg2, 128, 0, stream>>>(rpA, a_cols, 1, a_vals, 0, x, 1, Yb, N, nnz, nullptr, nullptr, flags);
    gemm_k<<<gg, 256, 0, stream>>>(Yb, w_sd, biasf, nullptr, d_out, N, flags);
    spmm_k<<<sg2, 128, 0, stream>>>(rpT, tSrc, 0, tValF, 1, x, 1, Yb, N, nnz, nullptr, nullptr, flags);
    gemm_k<<<gg, 256, 0, stream>>>(Yb, w_ds, nullptr, d_out, d_out, N, flags);
    spmm_k<<<sg2, 128, 0, stream>>>(rpT, tSrc, 0, tValF, 1, x, 1, gb, N, nnz, s1, nullptr, flags);
    spmm_k<<<sg2, 128, 0, stream>>>(rpA, a_cols, 1, a_vals, 0, gb, 0, Yb, N, nnz, nullptr, s1, flags);
    gemm_k<<<gg, 256, 0, stream>>>(Yb, w0, nullptr, d_out, d_out, N, flags);
    spmm_k<<<sg2, 128, 0, stream>>>(rpA, a_cols, 1, a_vals, 0, x, 1, gb, N, nnz, s2, nullptr, flags);
    spmm_k<<<sg2, 128, 0, stream>>>(rpT, tSrc, 0, tValF, 1, gb, 0, Yb, N, nnz, nullptr, s2, flags);
    gemm_k<<<gg, 256, 0, stream>>>(Yb, w1, nullptr, d_out, d_out, N, flags);
    spmm_k<<<sg2, 128, 0, stream>>>(rpA, a_cols, 1, a_vals, 0, x, 1, gb, N, nnz, s4, nullptr, flags);
    spmm_k<<<sg2, 128, 0, stream>>>(rpA, a_cols, 1, a_vals, 0, gb, 0, Yb, N, nnz, nullptr, s3, flags);
    gemm_k<<<gg, 256, 0, stream>>>(Yb, w2, nullptr, d_out, d_out, N, flags);
    spmm_k<<<sg2, 128, 0, stream>>>(rpT, tSrc, 0, tValF, 1, x, 1, gb, N, nnz, s3, nullptr, flags);
    spmm_k<<<sg2, 128, 0, stream>>>(rpT, tSrc, 0, tValF, 1, gb, 0, Yb, N, nnz, nullptr, s4, flags);
    gemm_k<<<gg, 256, 0, stream>>>(Yb, w3, nullptr, d_out, d_out, N, flags);
  }
}